// Round 1
// baseline (744.849 us; speedup 1.0000x reference)
//
#include <hip/hip_runtime.h>

typedef __attribute__((ext_vector_type(8))) short short8;
typedef __attribute__((ext_vector_type(4))) float f32x4;

#define HH 256
#define WW 256

__device__ inline unsigned int f2bf(float x) {
  unsigned int u = __float_as_uint(x);
  return (u + 0x7fffu + ((u >> 16) & 1u)) >> 16;   // RTNE truncation to bf16
}
__device__ inline unsigned int pack2(float a, float b) {
  return f2bf(a) | (f2bf(b) << 16);
}

// ---------------- transpose x (fp32 NCHW) -> xcl bf16 [B][H][W][64] ----------------
__global__ __launch_bounds__(256) void xpose_k(const float* __restrict__ x,
                                               unsigned short* __restrict__ xcl) {
  const int t = threadIdx.x;
  const int ci = t & 63;
  const int wv = t >> 6;
  const int x0 = blockIdx.x * 64;
  const int y  = blockIdx.y;
  const int b  = blockIdx.z;
  const float* src = x + ((size_t)(b * 64 + ci) * HH + y) * WW + x0 + wv;
  unsigned short* dst = xcl + ((size_t)(b * HH + y) * WW + x0 + wv) * 64 + ci;
#pragma unroll
  for (int k = 0; k < 16; ++k)
    dst[(size_t)k * 4 * 64] = (unsigned short)f2bf(src[4 * k]);
}

// ---------------- weight norm -> [tap][co][ci] bf16 ----------------
template <int COUT, int CINK>
__global__ __launch_bounds__(256) void wnorm_k(const float* __restrict__ v,
                                               const float* __restrict__ g,
                                               unsigned short* __restrict__ out) {
  constexpr int N = CINK * 9;
  const int co = blockIdx.x, t = threadIdx.x;
  const float* vb = v + (size_t)co * N;
  float s = 0.f;
  for (int i = t; i < N; i += 256) { float a = vb[i]; s += a * a; }
  for (int off = 32; off > 0; off >>= 1) s += __shfl_xor(s, off, 64);
  __shared__ float red[4];
  if ((t & 63) == 0) red[t >> 6] = s;
  __syncthreads();
  const float tot = red[0] + red[1] + red[2] + red[3];
  const float sc = g[co] / sqrtf(tot);
  for (int i = t; i < N; i += 256) {
    int ci = i / 9, tap = i - 9 * (i / 9);
    out[((size_t)tap * COUT + co) * CINK + ci] = (unsigned short)f2bf(vb[i] * sc);
  }
}

// ---------------- dyn bank norms ----------------
__global__ __launch_bounds__(256) void dynnorm_k(const float* __restrict__ dyn_v,
                                                 const float* __restrict__ dyn_g,
                                                 float* __restrict__ dscale) {
  const int k = blockIdx.x, t = threadIdx.x;
  const float* vb = dyn_v + (size_t)k * 36864;
  float s = 0.f;
  for (int i = t; i < 36864; i += 256) { float a = vb[i]; s += a * a; }
  for (int off = 32; off > 0; off >>= 1) s += __shfl_xor(s, off, 64);
  __shared__ float red[4];
  if ((t & 63) == 0) red[t >> 6] = s;
  __syncthreads();
  if (t == 0) dscale[k] = dyn_g[k] / sqrtf(red[0] + red[1] + red[2] + red[3]);
}

// ---------------- per-sample mixed dyn weights + bias; zero psum ----------------
__global__ __launch_bounds__(256) void mix_k(const float* __restrict__ scale,
                                             const float* __restrict__ att_w,
                                             const float* __restrict__ att_b,
                                             const float* __restrict__ dyn_v,
                                             const float* __restrict__ dyn_b,
                                             const float* __restrict__ dscale,
                                             unsigned short* __restrict__ wbt,
                                             float* __restrict__ bias_b,
                                             float* __restrict__ psum) {
  const int blk = blockIdx.x;
  const int b = blk >> 6, co = blk & 63;
  const int t = threadIdx.x;
  float att[4], wsc[4];
  const float sc = scale[b];
  float mx = -1e30f;
#pragma unroll
  for (int k = 0; k < 4; ++k) { att[k] = sc * att_w[k] + att_b[k]; mx = fmaxf(mx, att[k]); }
  float den = 0.f;
#pragma unroll
  for (int k = 0; k < 4; ++k) { att[k] = expf(att[k] - mx); den += att[k]; }
#pragma unroll
  for (int k = 0; k < 4; ++k) { att[k] /= den; wsc[k] = att[k] * dscale[k]; }
  for (int i = t; i < 576; i += 256) {
    int ci = i / 9, tap = i - 9 * (i / 9);
    float w = 0.f;
#pragma unroll
    for (int k = 0; k < 4; ++k)
      w += wsc[k] * dyn_v[(((size_t)k * 64 + co) * 64 + ci) * 9 + tap];
    wbt[(((size_t)b * 9 + tap) * 64 + co) * 64 + ci] = (unsigned short)f2bf(w);
  }
  if (t == 0) {
    float bb = 0.f;
#pragma unroll
    for (int k = 0; k < 4; ++k) bb += att[k] * dyn_b[k * 64 + co];
    bias_b[blk] = bb;
  }
  if (blk == 0) psum[t] = 0.f;
}

// ---------------- MFMA 3x3 conv: channel-last in, 64co x (8x32)px tile ----------------
template <int CIN, int COUT, int OSTR, bool RELU, bool DYN>
__global__ __launch_bounds__(256) void conv3x3_mfma(const unsigned short* __restrict__ in_cl,
                                                    const unsigned short* __restrict__ wt,
                                                    const float* __restrict__ bias,
                                                    unsigned short* __restrict__ out_cl,
                                                    float* __restrict__ y_out,
                                                    float* __restrict__ psum) {
  constexpr int CO_TILES = COUT / 64;
  const int tid = threadIdx.x;
  const int lane = tid & 63;
  const int wv = tid >> 6;
  const int l15 = lane & 15;
  const int lg = lane >> 4;
  const int cot = blockIdx.z % CO_TILES;
  const int bz = blockIdx.z / CO_TILES;
  const int x0 = blockIdx.x * 32;
  const int y0 = blockIdx.y * 8;
  const int co0 = cot * 64;

  const unsigned short* inb = in_cl + (size_t)bz * HH * WW * CIN;
  const unsigned short* wtb = wt + (DYN ? (size_t)bz * 9 * 64 * 64 : (size_t)0);
  const float* biasb = bias + (DYN ? bz * 64 : 0);

  __shared__ unsigned short tile[10 * 34 * 64];  // 43.5 KB, XOR-swizzled

  f32x4 acc[4][4];
#pragma unroll
  for (int m = 0; m < 4; ++m)
#pragma unroll
    for (int n = 0; n < 4; ++n) acc[m][n] = (f32x4){0.f, 0.f, 0.f, 0.f};

#pragma unroll 1
  for (int chunk = 0; chunk < CIN / 64; ++chunk) {
    if (chunk) __syncthreads();
    // stage [10 rows][34 cols][64 ci] bf16, zero-padded, swizzle byte^=(col&7)<<4
    for (int u = tid; u < 10 * 34 * 8; u += 256) {
      int ci8 = u & 7;
      int px = u >> 3;
      int col = px % 34;
      int row = px / 34;
      int gyy = y0 - 1 + row;
      int gxx = x0 - 1 + col;
      uint4 val = {0u, 0u, 0u, 0u};
      if ((unsigned)gyy < (unsigned)HH && (unsigned)gxx < (unsigned)WW)
        val = *(const uint4*)(inb + ((size_t)(gyy * WW + gxx)) * CIN + chunk * 64 + ci8 * 8);
      const int byt = px * 128 + ((ci8 * 16) ^ ((col & 7) << 4));
      *(uint4*)((char*)tile + byt) = val;
    }
    __syncthreads();
#pragma unroll
    for (int tap = 0; tap < 9; ++tap) {
      const int dy = tap / 3;
      const int dx = tap - 3 * dy;
      short8 A[2][4];
#pragma unroll
      for (int s = 0; s < 2; ++s)
#pragma unroll
        for (int m = 0; m < 4; ++m)
          A[s][m] = *(const short8*)(wtb + (((size_t)tap * COUT + co0 + 16 * m + l15) * CIN +
                                            chunk * 64 + s * 32 + lg * 8));
#pragma unroll
      for (int s = 0; s < 2; ++s) {
#pragma unroll
        for (int n = 0; n < 4; ++n) {
          const int brow = 2 * wv + (n >> 1) + dy;
          const int bcol = 16 * (n & 1) + l15 + dx;
          const int byt = (brow * 34 + bcol) * 128 + ((lg * 16 + s * 64) ^ ((bcol & 7) << 4));
          short8 Bf = *(const short8*)((const char*)tile + byt);
#pragma unroll
          for (int m = 0; m < 4; ++m)
            acc[m][n] = __builtin_amdgcn_mfma_f32_16x16x32_bf16(A[s][m], Bf, acc[m][n], 0, 0, 0);
        }
      }
    }
  }

  float scol[4][4];
  if (DYN) {
#pragma unroll
    for (int m = 0; m < 4; ++m)
#pragma unroll
      for (int f = 0; f < 4; ++f) scol[m][f] = 0.f;
  }

#pragma unroll
  for (int m = 0; m < 4; ++m) {
    const f32x4 bs = *(const f32x4*)(biasb + co0 + 16 * m + 4 * lg);
#pragma unroll
    for (int n = 0; n < 4; ++n) {
      f32x4 v = acc[m][n] + bs;
      if (RELU) {
        v.x = fmaxf(v.x, 0.f); v.y = fmaxf(v.y, 0.f);
        v.z = fmaxf(v.z, 0.f); v.w = fmaxf(v.w, 0.f);
      }
      const int yy = y0 + 2 * wv + (n >> 1);
      const int xx = x0 + 16 * (n & 1) + l15;
      if (!DYN) {
        uint2 pk;
        pk.x = pack2(v.x, v.y);
        pk.y = pack2(v.z, v.w);
        *(uint2*)(out_cl + ((size_t)(yy * WW + xx)) * OSTR + co0 + 16 * m + 4 * lg) = pk;
      } else {
        const size_t base = ((size_t)(bz * 64 + 16 * m + 4 * lg) * HH + yy) * WW + xx;
        y_out[base]             = v.x;
        y_out[base + 1 * 65536] = v.y;
        y_out[base + 2 * 65536] = v.z;
        y_out[base + 3 * 65536] = v.w;
        scol[m][0] += v.x; scol[m][1] += v.y; scol[m][2] += v.z; scol[m][3] += v.w;
      }
    }
  }
  if (DYN) {
#pragma unroll
    for (int m = 0; m < 4; ++m)
#pragma unroll
      for (int f = 0; f < 4; ++f) {
        float r = scol[m][f];
        r += __shfl_xor(r, 1, 64);
        r += __shfl_xor(r, 2, 64);
        r += __shfl_xor(r, 4, 64);
        r += __shfl_xor(r, 8, 64);
        if (l15 == 0) atomicAdd(&psum[bz * 64 + 16 * m + 4 * lg + f], r);
      }
  }
}

// ---------------- SE gate ----------------
__global__ __launch_bounds__(256) void gate_k(const float* __restrict__ psum,
                                              const float* __restrict__ se_w1,
                                              const float* __restrict__ se_w2,
                                              float* __restrict__ gate) {
  __shared__ float p_s[256], h_s[64];
  const int t = threadIdx.x;
  p_s[t] = psum[t] * (1.f / 65536.f);
  __syncthreads();
  if (t < 64) {
    const int b = t >> 4, j = t & 15;
    float h = 0.f;
    for (int c = 0; c < 64; ++c) h += p_s[b * 64 + c] * se_w1[j * 64 + c];
    h_s[t] = fmaxf(h, 0.f);
  }
  __syncthreads();
  const int b = t >> 6, c = t & 63;
  float s = 0.f;
  for (int j = 0; j < 16; ++j) s += h_s[b * 16 + j] * se_w2[c * 16 + j];
  gate[t] = 1.f / (1.f + expf(-s));
}

// ---------------- final: out = x + y*gate (in-place on d_out) ----------------
__global__ __launch_bounds__(256) void final_k(const float* __restrict__ x,
                                               const float* __restrict__ gate,
                                               float* __restrict__ out) {
  const size_t i = ((size_t)blockIdx.x * 256 + threadIdx.x) * 4;
  f32x4 yv = *(f32x4*)(out + i);
  const f32x4 xv = *(const f32x4*)(x + i);
  const float g = gate[(int)(i >> 16)];
  yv = xv + yv * g;
  *(f32x4*)(out + i) = yv;
}

// ---------------- workspace layout ----------------
static constexpr size_t SZ_XCL = (size_t)4 * 256 * 256 * 64 * 2;   // 33.55 MB
static constexpr size_t SZ_R   = (size_t)256 * 256 * 256 * 2;      // 33.55 MB (one batch of r)
static constexpr size_t SZ_R2  = (size_t)4 * 256 * 256 * 64 * 2;   // 33.55 MB
static constexpr size_t OFF_XCL = 0;
static constexpr size_t OFF_R   = OFF_XCL + SZ_XCL;
static constexpr size_t OFF_R2  = OFF_R + SZ_R;
static constexpr size_t OFF_W1T = OFF_R2 + SZ_R2;
static constexpr size_t OFF_W2T = OFF_W1T + (size_t)9 * 256 * 64 * 2;
static constexpr size_t OFF_WBT = OFF_W2T + (size_t)9 * 64 * 256 * 2;
static constexpr size_t OFF_DSC = OFF_WBT + (size_t)4 * 9 * 64 * 64 * 2;
static constexpr size_t OFF_BB  = OFF_DSC + 64;
static constexpr size_t OFF_PS  = OFF_BB + 1024;
static constexpr size_t OFF_GT  = OFF_PS + 1024;
static constexpr size_t WS_NEED = OFF_GT + 1024;

extern "C" void kernel_launch(void* const* d_in, const int* in_sizes, int n_in,
                              void* d_out, int out_size, void* d_ws, size_t ws_size,
                              hipStream_t stream) {
  (void)in_sizes; (void)n_in; (void)out_size;
  if (ws_size < WS_NEED) return;  // need ~102 MB scratch

  const float* x     = (const float*)d_in[0];
  const float* scale = (const float*)d_in[1];
  const float* v1    = (const float*)d_in[2];
  const float* g1    = (const float*)d_in[3];
  const float* b1    = (const float*)d_in[4];
  const float* v2    = (const float*)d_in[5];
  const float* g2    = (const float*)d_in[6];
  const float* b2    = (const float*)d_in[7];
  const float* dyn_v = (const float*)d_in[8];
  const float* dyn_g = (const float*)d_in[9];
  const float* dyn_b = (const float*)d_in[10];
  const float* att_w = (const float*)d_in[11];
  const float* att_b = (const float*)d_in[12];
  const float* se_w1 = (const float*)d_in[13];
  const float* se_w2 = (const float*)d_in[14];
  float* out = (float*)d_out;

  char* ws = (char*)d_ws;
  unsigned short* xcl  = (unsigned short*)(ws + OFF_XCL);
  unsigned short* rbuf = (unsigned short*)(ws + OFF_R);
  unsigned short* r2   = (unsigned short*)(ws + OFF_R2);
  unsigned short* w1t  = (unsigned short*)(ws + OFF_W1T);
  unsigned short* w2t  = (unsigned short*)(ws + OFF_W2T);
  unsigned short* wbt  = (unsigned short*)(ws + OFF_WBT);
  float* dscale = (float*)(ws + OFF_DSC);
  float* bias_b = (float*)(ws + OFF_BB);
  float* psum   = (float*)(ws + OFF_PS);
  float* gate   = (float*)(ws + OFF_GT);

  xpose_k<<<dim3(4, 256, 4), 256, 0, stream>>>(x, xcl);
  wnorm_k<256, 64><<<256, 256, 0, stream>>>(v1, g1, w1t);
  wnorm_k<64, 256><<<64, 256, 0, stream>>>(v2, g2, w2t);
  dynnorm_k<<<4, 256, 0, stream>>>(dyn_v, dyn_g, dscale);
  mix_k<<<256, 256, 0, stream>>>(scale, att_w, att_b, dyn_v, dyn_b, dscale, wbt, bias_b, psum);

  for (int b = 0; b < 4; ++b) {
    conv3x3_mfma<64, 256, 256, true, false><<<dim3(8, 32, 4), 256, 0, stream>>>(
        xcl + (size_t)b * 256 * 256 * 64, w1t, b1, rbuf, nullptr, nullptr);
    conv3x3_mfma<256, 64, 64, false, false><<<dim3(8, 32, 1), 256, 0, stream>>>(
        rbuf, w2t, b2, r2 + (size_t)b * 256 * 256 * 64, nullptr, nullptr);
  }
  conv3x3_mfma<64, 64, 64, false, true><<<dim3(8, 32, 4), 256, 0, stream>>>(
      r2, wbt, bias_b, nullptr, out, psum);

  gate_k<<<1, 256, 0, stream>>>(psum, se_w1, se_w2, gate);
  final_k<<<16384, 256, 0, stream>>>(x, gate, out);
}

// Round 2
// 553.434 us; speedup vs baseline: 1.3459x; 1.3459x over previous
//
#include <hip/hip_runtime.h>

typedef __attribute__((ext_vector_type(8))) short short8;
typedef __attribute__((ext_vector_type(4))) float f32x4;

#define HH 256
#define WW 256

__device__ inline unsigned int f2bf(float x) {
  unsigned int u = __float_as_uint(x);
  return (u + 0x7fffu + ((u >> 16) & 1u)) >> 16;   // RTNE truncation to bf16
}
__device__ inline unsigned int pack2(float a, float b) {
  return f2bf(a) | (f2bf(b) << 16);
}

// ---------------- transpose x (fp32 NCHW) -> xcl bf16 [B][H][W][64] ----------------
__global__ __launch_bounds__(256) void xpose_k(const float* __restrict__ x,
                                               unsigned short* __restrict__ xcl) {
  const int t = threadIdx.x;
  const int ci = t & 63;
  const int wv = t >> 6;
  const int x0 = blockIdx.x * 64;
  const int y  = blockIdx.y;
  const int b  = blockIdx.z;
  const float* src = x + ((size_t)(b * 64 + ci) * HH + y) * WW + x0 + wv;
  unsigned short* dst = xcl + ((size_t)(b * HH + y) * WW + x0 + wv) * 64 + ci;
#pragma unroll
  for (int k = 0; k < 16; ++k)
    dst[(size_t)k * 4 * 64] = (unsigned short)f2bf(src[4 * k]);
}

// ---------------- weight norm -> [tap][co][ci] bf16 ----------------
template <int COUT, int CINK>
__global__ __launch_bounds__(256) void wnorm_k(const float* __restrict__ v,
                                               const float* __restrict__ g,
                                               unsigned short* __restrict__ out) {
  constexpr int N = CINK * 9;
  const int co = blockIdx.x, t = threadIdx.x;
  const float* vb = v + (size_t)co * N;
  float s = 0.f;
  for (int i = t; i < N; i += 256) { float a = vb[i]; s += a * a; }
  for (int off = 32; off > 0; off >>= 1) s += __shfl_xor(s, off, 64);
  __shared__ float red[4];
  if ((t & 63) == 0) red[t >> 6] = s;
  __syncthreads();
  const float tot = red[0] + red[1] + red[2] + red[3];
  const float sc = g[co] / sqrtf(tot);
  for (int i = t; i < N; i += 256) {
    int ci = i / 9, tap = i - 9 * (i / 9);
    out[((size_t)tap * COUT + co) * CINK + ci] = (unsigned short)f2bf(vb[i] * sc);
  }
}

// ---------------- dyn bank norms ----------------
__global__ __launch_bounds__(256) void dynnorm_k(const float* __restrict__ dyn_v,
                                                 const float* __restrict__ dyn_g,
                                                 float* __restrict__ dscale) {
  const int k = blockIdx.x, t = threadIdx.x;
  const float* vb = dyn_v + (size_t)k * 36864;
  float s = 0.f;
  for (int i = t; i < 36864; i += 256) { float a = vb[i]; s += a * a; }
  for (int off = 32; off > 0; off >>= 1) s += __shfl_xor(s, off, 64);
  __shared__ float red[4];
  if ((t & 63) == 0) red[t >> 6] = s;
  __syncthreads();
  if (t == 0) dscale[k] = dyn_g[k] / sqrtf(red[0] + red[1] + red[2] + red[3]);
}

// ---------------- per-sample mixed dyn weights + bias ----------------
__global__ __launch_bounds__(256) void mix_k(const float* __restrict__ scale,
                                             const float* __restrict__ att_w,
                                             const float* __restrict__ att_b,
                                             const float* __restrict__ dyn_v,
                                             const float* __restrict__ dyn_b,
                                             const float* __restrict__ dscale,
                                             unsigned short* __restrict__ wbt,
                                             float* __restrict__ bias_b) {
  const int blk = blockIdx.x;
  const int b = blk >> 6, co = blk & 63;
  const int t = threadIdx.x;
  float att[4], wsc[4];
  const float sc = scale[b];
  float mx = -1e30f;
#pragma unroll
  for (int k = 0; k < 4; ++k) { att[k] = sc * att_w[k] + att_b[k]; mx = fmaxf(mx, att[k]); }
  float den = 0.f;
#pragma unroll
  for (int k = 0; k < 4; ++k) { att[k] = expf(att[k] - mx); den += att[k]; }
#pragma unroll
  for (int k = 0; k < 4; ++k) { att[k] /= den; wsc[k] = att[k] * dscale[k]; }
  for (int i = t; i < 576; i += 256) {
    int ci = i / 9, tap = i - 9 * (i / 9);
    float w = 0.f;
#pragma unroll
    for (int k = 0; k < 4; ++k)
      w += wsc[k] * dyn_v[(((size_t)k * 64 + co) * 64 + ci) * 9 + tap];
    wbt[(((size_t)b * 9 + tap) * 64 + co) * 64 + ci] = (unsigned short)f2bf(w);
  }
  if (t == 0) {
    float bb = 0.f;
#pragma unroll
    for (int k = 0; k < 4; ++k) bb += att[k] * dyn_b[k * 64 + co];
    bias_b[blk] = bb;
  }
}

// ---------------- MFMA 3x3 conv: channel-last in, 64co x (8x32)px tile ----------------
template <int CIN, int COUT, int OSTR, bool RELU, bool DYN>
__global__ __launch_bounds__(256) void conv3x3_mfma(const unsigned short* __restrict__ in_cl,
                                                    const unsigned short* __restrict__ wt,
                                                    const float* __restrict__ bias,
                                                    unsigned short* __restrict__ out_cl,
                                                    float* __restrict__ y_out,
                                                    float* __restrict__ pblk) {
  constexpr int CO_TILES = COUT / 64;
  const int tid = threadIdx.x;
  const int lane = tid & 63;
  const int wv = tid >> 6;
  const int l15 = lane & 15;
  const int lg = lane >> 4;
  const int cot = blockIdx.z % CO_TILES;
  const int bz = blockIdx.z / CO_TILES;
  const int x0 = blockIdx.x * 32;
  const int y0 = blockIdx.y * 8;
  const int co0 = cot * 64;

  const unsigned short* inb = in_cl + (size_t)bz * HH * WW * CIN;
  const unsigned short* wtb = wt + (DYN ? (size_t)bz * 9 * 64 * 64 : (size_t)0);
  const float* biasb = bias + (DYN ? bz * 64 : 0);

  __shared__ unsigned short tile[10 * 34 * 64];  // 43.5 KB, XOR-swizzled

  f32x4 acc[4][4];
#pragma unroll
  for (int m = 0; m < 4; ++m)
#pragma unroll
    for (int n = 0; n < 4; ++n) acc[m][n] = (f32x4){0.f, 0.f, 0.f, 0.f};

#pragma unroll 1
  for (int chunk = 0; chunk < CIN / 64; ++chunk) {
    if (chunk) __syncthreads();
    // stage [10 rows][34 cols][64 ci] bf16, zero-padded, swizzle byte^=(col&7)<<4
    for (int u = tid; u < 10 * 34 * 8; u += 256) {
      int ci8 = u & 7;
      int px = u >> 3;
      int col = px % 34;
      int row = px / 34;
      int gyy = y0 - 1 + row;
      int gxx = x0 - 1 + col;
      uint4 val = {0u, 0u, 0u, 0u};
      if ((unsigned)gyy < (unsigned)HH && (unsigned)gxx < (unsigned)WW)
        val = *(const uint4*)(inb + ((size_t)(gyy * WW + gxx)) * CIN + chunk * 64 + ci8 * 8);
      const int byt = px * 128 + ((ci8 * 16) ^ ((col & 7) << 4));
      *(uint4*)((char*)tile + byt) = val;
    }
    __syncthreads();
#pragma unroll
    for (int tap = 0; tap < 9; ++tap) {
      const int dy = tap / 3;
      const int dx = tap - 3 * dy;
      short8 A[2][4];
#pragma unroll
      for (int s = 0; s < 2; ++s)
#pragma unroll
        for (int m = 0; m < 4; ++m)
          A[s][m] = *(const short8*)(wtb + (((size_t)tap * COUT + co0 + 16 * m + l15) * CIN +
                                            chunk * 64 + s * 32 + lg * 8));
#pragma unroll
      for (int s = 0; s < 2; ++s) {
#pragma unroll
        for (int n = 0; n < 4; ++n) {
          const int brow = 2 * wv + (n >> 1) + dy;
          const int bcol = 16 * (n & 1) + l15 + dx;
          const int byt = (brow * 34 + bcol) * 128 + ((lg * 16 + s * 64) ^ ((bcol & 7) << 4));
          short8 Bf = *(const short8*)((const char*)tile + byt);
#pragma unroll
          for (int m = 0; m < 4; ++m)
            acc[m][n] = __builtin_amdgcn_mfma_f32_16x16x32_bf16(A[s][m], Bf, acc[m][n], 0, 0, 0);
        }
      }
    }
  }

  float scol[4][4];
  if (DYN) {
#pragma unroll
    for (int m = 0; m < 4; ++m)
#pragma unroll
      for (int f = 0; f < 4; ++f) scol[m][f] = 0.f;
  }

#pragma unroll
  for (int m = 0; m < 4; ++m) {
    const f32x4 bs = *(const f32x4*)(biasb + co0 + 16 * m + 4 * lg);
#pragma unroll
    for (int n = 0; n < 4; ++n) {
      f32x4 v = acc[m][n] + bs;
      if (RELU) {
        v.x = fmaxf(v.x, 0.f); v.y = fmaxf(v.y, 0.f);
        v.z = fmaxf(v.z, 0.f); v.w = fmaxf(v.w, 0.f);
      }
      const int yy = y0 + 2 * wv + (n >> 1);
      const int xx = x0 + 16 * (n & 1) + l15;
      if (!DYN) {
        uint2 pk;
        pk.x = pack2(v.x, v.y);
        pk.y = pack2(v.z, v.w);
        *(uint2*)(out_cl + (size_t)bz * HH * WW * OSTR +
                  ((size_t)(yy * WW + xx)) * OSTR + co0 + 16 * m + 4 * lg) = pk;
      } else {
        const size_t base = ((size_t)(bz * 64 + 16 * m + 4 * lg) * HH + yy) * WW + xx;
        y_out[base]             = v.x;
        y_out[base + 1 * 65536] = v.y;
        y_out[base + 2 * 65536] = v.z;
        y_out[base + 3 * 65536] = v.w;
        scol[m][0] += v.x; scol[m][1] += v.y; scol[m][2] += v.z; scol[m][3] += v.w;
      }
    }
  }
  if (DYN) {
    // reduce over the 16 px lanes (l15 bits) -> every lane holds its lg-group sum
#pragma unroll
    for (int m = 0; m < 4; ++m)
#pragma unroll
      for (int f = 0; f < 4; ++f) {
        float r = scol[m][f];
        r += __shfl_xor(r, 1, 64);
        r += __shfl_xor(r, 2, 64);
        r += __shfl_xor(r, 4, 64);
        r += __shfl_xor(r, 8, 64);
        scol[m][f] = r;
      }
    __syncthreads();  // tile no longer needed; reuse as fp32 scratch
    float* red = (float*)tile;
    if (l15 == 0) {
#pragma unroll
      for (int m = 0; m < 4; ++m)
#pragma unroll
        for (int f = 0; f < 4; ++f)
          red[wv * 64 + 16 * m + 4 * lg + f] = scol[m][f];
    }
    __syncthreads();
    if (tid < 64) {
      const float s = red[tid] + red[64 + tid] + red[128 + tid] + red[192 + tid];
      pblk[((size_t)bz * 256 + blockIdx.y * 8 + blockIdx.x) * 64 + tid] = s;
    }
  }
}

// ---------------- SE gate: reduce per-block partials, 2-layer MLP ----------------
__global__ __launch_bounds__(256) void gate_k(const float* __restrict__ pblk,
                                              const float* __restrict__ se_w1,
                                              const float* __restrict__ se_w2,
                                              float* __restrict__ gate) {
  __shared__ float p_s[256], h_s[64];
  const int t = threadIdx.x;
  const int b = t >> 6, c = t & 63;
  float s = 0.f;
  for (int blk = 0; blk < 256; ++blk)
    s += pblk[((size_t)b * 256 + blk) * 64 + c];
  p_s[t] = s * (1.f / 65536.f);
  __syncthreads();
  if (t < 64) {
    const int bb = t >> 4, j = t & 15;
    float h = 0.f;
    for (int cc = 0; cc < 64; ++cc) h += p_s[bb * 64 + cc] * se_w1[j * 64 + cc];
    h_s[t] = fmaxf(h, 0.f);
  }
  __syncthreads();
  float acc = 0.f;
  for (int j = 0; j < 16; ++j) acc += h_s[b * 16 + j] * se_w2[c * 16 + j];
  gate[t] = 1.f / (1.f + expf(-acc));
}

// ---------------- final: out = x + y*gate (in-place on d_out) ----------------
__global__ __launch_bounds__(256) void final_k(const float* __restrict__ x,
                                               const float* __restrict__ gate,
                                               float* __restrict__ out) {
  const size_t i = ((size_t)blockIdx.x * 256 + threadIdx.x) * 4;
  f32x4 yv = *(f32x4*)(out + i);
  const f32x4 xv = *(const f32x4*)(x + i);
  const float g = gate[(int)(i >> 16)];
  yv = xv + yv * g;
  *(f32x4*)(out + i) = yv;
}

// ---------------- workspace sizes ----------------
static constexpr size_t MB = 1024 * 1024;
static constexpr size_t SZ_XCL = (size_t)4 * 256 * 256 * 64 * 2;   // 33.55 MB
static constexpr size_t SZ_W   = (size_t)9 * 256 * 64 * 2;         // 294912
static constexpr size_t SZ_PBLK = (size_t)4 * 256 * 64 * 4;        // 262144

// fallback layout (fits round-1 footprint):
static constexpr size_t F_XCL = 0;
static constexpr size_t F_R   = F_XCL + SZ_XCL;                    // 1 batch of r (33.55 MB)
static constexpr size_t F_R2  = F_R + SZ_XCL;
static constexpr size_t F_W1T = F_R2 + SZ_XCL;
static constexpr size_t F_W2T = F_W1T + SZ_W;
static constexpr size_t F_WBT = F_W2T + SZ_W;
static constexpr size_t F_DSC = F_WBT + SZ_W;
static constexpr size_t F_BB  = F_DSC + 256;
static constexpr size_t F_GT  = F_BB + 1024;
static constexpr size_t WS_SMALL = F_GT + 1024;
// pblk aliases xcl (dead after conv1) in fallback mode.

// batched layout: r for all 4 batches; r2 aliases xcl (dead after conv1)
static constexpr size_t B_XCL = 0;                                 // also r2
static constexpr size_t B_R   = B_XCL + SZ_XCL;
static constexpr size_t B_W1T = B_R + 4 * SZ_XCL;                  // 134.2 MB of r
static constexpr size_t B_W2T = B_W1T + SZ_W;
static constexpr size_t B_WBT = B_W2T + SZ_W;
static constexpr size_t B_DSC = B_WBT + SZ_W;
static constexpr size_t B_BB  = B_DSC + 256;
static constexpr size_t B_GT  = B_BB + 1024;
static constexpr size_t B_PBLK = B_GT + 1024;
static constexpr size_t WS_BIG = B_PBLK + SZ_PBLK;

extern "C" void kernel_launch(void* const* d_in, const int* in_sizes, int n_in,
                              void* d_out, int out_size, void* d_ws, size_t ws_size,
                              hipStream_t stream) {
  (void)in_sizes; (void)n_in; (void)out_size;
  if (ws_size < WS_SMALL) return;

  const float* x     = (const float*)d_in[0];
  const float* scale = (const float*)d_in[1];
  const float* v1    = (const float*)d_in[2];
  const float* g1    = (const float*)d_in[3];
  const float* b1    = (const float*)d_in[4];
  const float* v2    = (const float*)d_in[5];
  const float* g2    = (const float*)d_in[6];
  const float* b2    = (const float*)d_in[7];
  const float* dyn_v = (const float*)d_in[8];
  const float* dyn_g = (const float*)d_in[9];
  const float* dyn_b = (const float*)d_in[10];
  const float* att_w = (const float*)d_in[11];
  const float* att_b = (const float*)d_in[12];
  const float* se_w1 = (const float*)d_in[13];
  const float* se_w2 = (const float*)d_in[14];
  float* out = (float*)d_out;

  char* ws = (char*)d_ws;
  const bool batched = ws_size >= WS_BIG;

  unsigned short* xcl  = (unsigned short*)(ws + (batched ? B_XCL : F_XCL));
  unsigned short* rbuf = (unsigned short*)(ws + (batched ? B_R   : F_R));
  unsigned short* r2   = (unsigned short*)(ws + (batched ? B_XCL : F_R2));
  unsigned short* w1t  = (unsigned short*)(ws + (batched ? B_W1T : F_W1T));
  unsigned short* w2t  = (unsigned short*)(ws + (batched ? B_W2T : F_W2T));
  unsigned short* wbt  = (unsigned short*)(ws + (batched ? B_WBT : F_WBT));
  float* dscale = (float*)(ws + (batched ? B_DSC : F_DSC));
  float* bias_b = (float*)(ws + (batched ? B_BB  : F_BB));
  float* gate   = (float*)(ws + (batched ? B_GT  : F_GT));
  float* pblk   = (float*)(ws + (batched ? B_PBLK : F_XCL));  // fallback: aliases dead xcl

  xpose_k<<<dim3(4, 256, 4), 256, 0, stream>>>(x, xcl);
  wnorm_k<256, 64><<<256, 256, 0, stream>>>(v1, g1, w1t);
  wnorm_k<64, 256><<<64, 256, 0, stream>>>(v2, g2, w2t);
  dynnorm_k<<<4, 256, 0, stream>>>(dyn_v, dyn_g, dscale);
  mix_k<<<256, 256, 0, stream>>>(scale, att_w, att_b, dyn_v, dyn_b, dscale, wbt, bias_b);

  if (batched) {
    conv3x3_mfma<64, 256, 256, true, false><<<dim3(8, 32, 16), 256, 0, stream>>>(
        xcl, w1t, b1, rbuf, nullptr, nullptr);
    conv3x3_mfma<256, 64, 64, false, false><<<dim3(8, 32, 4), 256, 0, stream>>>(
        rbuf, w2t, b2, r2, nullptr, nullptr);
  } else {
    for (int b = 0; b < 4; ++b) {
      conv3x3_mfma<64, 256, 256, true, false><<<dim3(8, 32, 4), 256, 0, stream>>>(
          xcl + (size_t)b * 256 * 256 * 64, w1t, b1, rbuf - (size_t)0, nullptr, nullptr);
      conv3x3_mfma<256, 64, 64, false, false><<<dim3(8, 32, 1), 256, 0, stream>>>(
          rbuf, w2t, b2, r2 + (size_t)b * 256 * 256 * 64, nullptr, nullptr);
    }
  }
  conv3x3_mfma<64, 64, 64, false, true><<<dim3(8, 32, 4), 256, 0, stream>>>(
      r2, wbt, bias_b, nullptr, out, pblk);

  gate_k<<<1, 256, 0, stream>>>(pblk, se_w1, se_w2, gate);
  final_k<<<16384, 256, 0, stream>>>(x, gate, out);
}